// Round 4
// baseline (94.641 us; speedup 1.0000x reference)
//
#include <hip/hip_runtime.h>
#include <math.h>

#define ALPHA 0.2f

typedef __attribute__((ext_vector_type(8))) short bf16x8;
typedef __attribute__((ext_vector_type(4))) float f32x4;
typedef __attribute__((ext_vector_type(4))) unsigned short us4;

// workspace layout (float offsets); ws_size = 512 MiB (verified via harness fill)
static constexpr size_t WS_ADJ  = 0;      // 1024 f32 adj_n (unused downstream, kept)
static constexpr size_t WS_WA1  = 1024;   // 32
static constexpr size_t WS_WA2  = 1056;   // 32  (contiguous with WA1)
static constexpr size_t WS_C12  = 1088;   // 2
static constexpr size_t WS_ADJT = 1664;   // 1024 bf16 = 512 f: adjT[j][i]
static constexpr size_t WS_WMF  = 2176;   // 1024 bf16 = 512 f: frag-ordered wm B-operand
static constexpr size_t WS_S1   = 2816;                     // N*H*W*V f32
static constexpr size_t WS_S2   = WS_S1 + (size_t)1048576;
static constexpr size_t WS_DEN  = WS_S2 + (size_t)1048576;  // [nh][i][j] = 1/denom
static constexpr size_t WS_WHT  = WS_DEN + (size_t)524288;  // 32768 sites x 1024 bf16: WhT[site][f][j]

__device__ __forceinline__ unsigned short f2bf(float x){
    union { float f; unsigned u; } c; c.f = x;
    unsigned r = c.u + 0x7FFFu + ((c.u >> 16) & 1u);
    return (unsigned short)(r >> 16);
}

__global__ __launch_bounds__(1024) void k0_prep(const float* __restrict__ W_map,
    const float* __restrict__ b_map, const float* __restrict__ a_attn,
    const float* __restrict__ B_adj, float* __restrict__ ws)
{
    __shared__ float lds[1024];
    __shared__ float d12[32];
    int tid = threadIdx.x;
    int i = tid >> 5, j = tid & 31;
    float a = B_adj[tid] + (i == j ? 1.0f : 0.0f);
    lds[tid] = a; __syncthreads();
    for (int s = 512; s > 0; s >>= 1) { if (tid < s) lds[tid] = fmaxf(lds[tid], lds[tid + s]); __syncthreads(); }
    float mx = lds[0]; __syncthreads();
    lds[tid] = a; __syncthreads();
    for (int s = 512; s > 0; s >>= 1) { if (tid < s) lds[tid] = fminf(lds[tid], lds[tid + s]); __syncthreads(); }
    float mn = lds[0]; __syncthreads();
    float nrm = (a - mn) / (mx - mn);
    lds[tid] = nrm; __syncthreads();
    if (tid < 32) {
        float s = 0.f;
        for (int jj = 0; jj < 32; ++jj) s += lds[tid * 32 + jj];
        d12[tid] = 1.0f / sqrtf(s);
    }
    __syncthreads();
    float adjn = d12[i] * nrm * d12[j];
    ws[WS_ADJ + tid] = adjn;
    ((unsigned short*)(ws + WS_ADJT))[j * 32 + i] = f2bf(adjn);   // adjT[j][i]
    // frag-ordered wm B-operand: idx = q*512 + l*8 + e  ->  wm[t=8*(l>>4)+e][f=(l&15)+16q]
    {
        int q = tid >> 9, rem = tid & 511, ll = rem >> 3, e = rem & 7;
        int t = 8 * (ll >> 4) + e, f = (ll & 15) + 16 * q;
        ((unsigned short*)(ws + WS_WMF))[tid] = f2bf(W_map[t * 32 + f]);
    }
    if (tid < 32) {
        float w1 = 0.f, w2 = 0.f;
        for (int f = 0; f < 32; ++f) {
            w1 += W_map[tid * 32 + f] * a_attn[f];
            w2 += W_map[tid * 32 + f] * a_attn[32 + f];
        }
        ws[WS_WA1 + tid] = w1; ws[WS_WA2 + tid] = w2;
    }
    if (tid == 0) {
        float c1 = 0.f, c2 = 0.f;
        for (int f = 0; f < 32; ++f) { c1 += b_map[f] * a_attn[f]; c2 += b_map[f] * a_attn[32 + f]; }
        ws[WS_C12] = c1; ws[WS_C12 + 1] = c2;
    }
}

__device__ __forceinline__ bf16x8 pack8(f32x4 a, f32x4 b){
    bf16x8 r;
    r[0]=(short)f2bf(a[0]); r[1]=(short)f2bf(a[1]); r[2]=(short)f2bf(a[2]); r[3]=(short)f2bf(a[3]);
    r[4]=(short)f2bf(b[0]); r[5]=(short)f2bf(b[1]); r[6]=(short)f2bf(b[2]); r[7]=(short)f2bf(b[3]);
    return r;
}
__device__ __forceinline__ void store_bf4(unsigned short* p, f32x4 v){
    us4 s; s[0]=f2bf(v[0]); s[1]=f2bf(v[1]); s[2]=f2bf(v[2]); s[3]=f2bf(v[3]);
    *(us4*)p = s;
}

// k1: per wave (one site): stream h once -> s1/s2 (VALU dot) + WhT bf16 (MFMA).
// One block = 4 waves = 4 sites.
__global__ __launch_bounds__(256) void k1_wh(const float* __restrict__ hin,
    const float* __restrict__ b_map, float* __restrict__ ws)
{
    __shared__ float hh[4][1024];   // per-wave h site [t][v] f32
    __shared__ float lwa[64];
    const int tid = threadIdx.x;
    const int wid = tid >> 6, l = tid & 63;
    const long site = (long)blockIdx.x * 4 + wid;
    const int fr = l & 15, g = l >> 4;

    if (tid < 64) lwa[tid] = ws[WS_WA1 + tid];     // wa1[0..31], wa2[0..31]
    bf16x8 wmF[2];
    {
        const short* wf = (const short*)(ws + WS_WMF);
        wmF[0] = *(const bf16x8*)(wf + l * 8);
        wmF[1] = *(const bf16x8*)(wf + 512 + l * 8);
    }
    const float c1 = ws[WS_C12], c2 = ws[WS_C12 + 1];

    {
        const f32x4* hs = (const f32x4*)(hin + site * 1024);
        f32x4* hd = (f32x4*)hh[wid];
        hd[l] = hs[l]; hd[l + 64] = hs[l + 64]; hd[l + 128] = hs[l + 128]; hd[l + 192] = hs[l + 192];
    }
    __syncthreads();

    // s1/s2: lanes 0-31 -> s1[i], lanes 32-63 -> s2[i]
    {
        const int half = l >> 5, i = l & 31;
        float acc = half ? c2 : c1;
#pragma unroll
        for (int t = 0; t < 32; ++t)
            acc = fmaf(hh[wid][t * 32 + i], lwa[half * 32 + t], acc);
        ws[(half ? WS_S2 : WS_S1) + site * 32 + i] = acc;
    }

    // Wh[j][f] = sum_t h[t][j] wm[t][f] + b[f]   (D[j][f]: A=hT-frag, B=wmF)
    {
        bf16x8 a[2];
#pragma unroll
        for (int p = 0; p < 2; ++p) {
            float x[8];
#pragma unroll
            for (int e = 0; e < 8; ++e) x[e] = hh[wid][(g * 8 + e) * 32 + fr + 16 * p];
            f32x4 lo = { x[0], x[1], x[2], x[3] }, hi = { x[4], x[5], x[6], x[7] };
            a[p] = pack8(lo, hi);
        }
        unsigned short* whp = (unsigned short*)(ws + WS_WHT) + site * 1024;
#pragma unroll
        for (int p = 0; p < 2; ++p)
#pragma unroll
            for (int q = 0; q < 2; ++q) {
                const float bb = b_map[fr + 16 * q];
                f32x4 c = { bb, bb, bb, bb };
                c = __builtin_amdgcn_mfma_f32_16x16x32_bf16(a[p], wmF[q], c, 0, 0, 0);
                // regs r: j = 4g+r+16p, f = fr+16q  ->  WhT[f][j] us4 (4 consecutive j)
                store_bf4(&whp[(fr + 16 * q) * 32 + 4 * g + 16 * p], c);
            }
    }
}

// rden[nh,i,j] = 1 / sum_w exp(lrelu(s1[i,w]+s2[j,w]))
__global__ __launch_bounds__(1024) void k2_denom(float* __restrict__ ws)
{
    __shared__ float ls1[2048], ls2[2048];
    int tid = threadIdx.x;
    long nh = blockIdx.x;
    const float* s1 = ws + WS_S1 + nh * 2048;
    const float* s2 = ws + WS_S2 + nh * 2048;
    ls1[tid] = s1[tid]; ls1[tid + 1024] = s1[tid + 1024];
    ls2[tid] = s2[tid]; ls2[tid + 1024] = s2[tid + 1024];
    __syncthreads();
    int i = tid >> 5, j = tid & 31;
    float sum = 0.f;
#pragma unroll
    for (int w = 0; w < 64; ++w) {
        float e = ls1[w * 32 + i] + ls2[w * 32 + j];
        e = e > 0.f ? e : ALPHA * e;
        sum += __expf(e);
    }
    ws[WS_DEN + nh * 1024 + tid] = 1.0f / sum;
}

__device__ __forceinline__ float elu(float x) { return x > 0.f ? x : __expf(x) - 1.0f; }

// k3: per wave (one site): at in-register -> M (MFMA) -> O = WhT x M (MFMA, WhT from global).
__global__ __launch_bounds__(256) void k3_main(const float* __restrict__ ws, float* __restrict__ out)
{
    __shared__ float denT[32 * 36];              // [j][i] pad36
    __shared__ unsigned short mtT[4][32 * 40];   // per-wave M as [j][j'] bf16 pad40

    const int tid = threadIdx.x;
    const int wid = tid >> 6, l = tid & 63;
    const long site = (long)blockIdx.x * 4 + wid;
    const int w = (int)(site & 63);
    const long nh = site >> 6;
    const int hh = (int)(nh & 63);
    const int n = (int)(nh >> 6);
    const int fr = l & 15, g = l >> 4;

    // block stage: denT[j][i] = rden[i][j]
    {
        f32x4 dv = ((const f32x4*)(ws + WS_DEN + nh * 1024))[tid];
        int di = tid >> 3, dj = (tid & 7) * 4;
        denT[(dj + 0) * 36 + di] = dv[0];
        denT[(dj + 1) * 36 + di] = dv[1];
        denT[(dj + 2) * 36 + di] = dv[2];
        denT[(dj + 3) * 36 + di] = dv[3];
    }
    // constant frags + WhT A-frags straight from global (coalesced b128)
    bf16x8 adjB[2], a3[2];
    {
        const short* adt = (const short*)(ws + WS_ADJT);
        const short* whp = (const short*)(ws + WS_WHT) + site * 1024;
#pragma unroll
        for (int q = 0; q < 2; ++q) {
            adjB[q] = *(const bf16x8*)(adt + (fr + 16 * q) * 32 + g * 8);
            a3[q]   = *(const bf16x8*)(whp + (fr + 16 * q) * 32 + g * 8);
        }
    }
    __syncthreads();

    // stage 2: M[j'][j] = sum_i at[i][j'] adj[i][j], at built in-register
    {
        f32x4 s1a = *(const f32x4*)(ws + WS_S1 + site * 32 + g * 8);
        f32x4 s1b = *(const f32x4*)(ws + WS_S1 + site * 32 + g * 8 + 4);
        float s2v[2] = { ws[WS_S2 + site * 32 + fr], ws[WS_S2 + site * 32 + fr + 16] };
        bf16x8 a2[2];
#pragma unroll
        for (int p = 0; p < 2; ++p) {
            f32x4 d0 = *(const f32x4*)&denT[(fr + 16 * p) * 36 + g * 8];
            f32x4 d1 = *(const f32x4*)&denT[(fr + 16 * p) * 36 + g * 8 + 4];
            f32x4 t0, t1;
#pragma unroll
            for (int e = 0; e < 4; ++e) {
                float ea = s1a[e] + s2v[p]; ea = ea > 0.f ? ea : ALPHA * ea;
                float eb = s1b[e] + s2v[p]; eb = eb > 0.f ? eb : ALPHA * eb;
                t0[e] = __expf(ea) * d0[e];
                t1[e] = __expf(eb) * d1[e];
            }
            a2[p] = pack8(t0, t1);
        }
#pragma unroll
        for (int p = 0; p < 2; ++p)
#pragma unroll
            for (int q = 0; q < 2; ++q) {
                f32x4 c = { 0.f, 0.f, 0.f, 0.f };
                c = __builtin_amdgcn_mfma_f32_16x16x32_bf16(a2[p], adjB[q], c, 0, 0, 0);
                store_bf4(&mtT[wid][(fr + 16 * q) * 40 + 4 * g + 16 * p], c);
            }
    }

    // stage 3: O[f][j] = sum_j' WhT[f][j'] M[j'][j]
    {
        bf16x8 b3[2];
#pragma unroll
        for (int q = 0; q < 2; ++q)
            b3[q] = *(const bf16x8*)&mtT[wid][(fr + 16 * q) * 40 + g * 8];
        const int hhi = hh >> 5, f3 = hh & 31;
#pragma unroll
        for (int p = 0; p < 2; ++p)
#pragma unroll
            for (int q = 0; q < 2; ++q) {
                f32x4 c = { 0.f, 0.f, 0.f, 0.f };
                c = __builtin_amdgcn_mfma_f32_16x16x32_bf16(a3[p], b3[q], c, 0, 0, 0);
#pragma unroll
                for (int r = 0; r < 4; ++r) {
                    int f = 16 * p + 4 * g + r;
                    int w3 = f * 2 + hhi;
                    out[((((long)n * 64 + w) * 64 + w3) * 32 + f3) * 32 + fr + 16 * q] = elu(c[r]);
                }
            }
    }
}

extern "C" void kernel_launch(void* const* d_in, const int* in_sizes, int n_in,
                              void* d_out, int out_size, void* d_ws, size_t ws_size,
                              hipStream_t stream) {
    (void)in_sizes; (void)n_in; (void)out_size; (void)ws_size;
    const float* hin    = (const float*)d_in[0];
    const float* W_map  = (const float*)d_in[1];
    const float* b_map  = (const float*)d_in[2];
    const float* a_attn = (const float*)d_in[3];
    const float* B_adj  = (const float*)d_in[4];
    float* out = (float*)d_out;
    float* ws  = (float*)d_ws;

    hipLaunchKernelGGL(k0_prep, dim3(1),    dim3(1024), 0, stream, W_map, b_map, a_attn, B_adj, ws);
    hipLaunchKernelGGL(k1_wh,   dim3(8192), dim3(256),  0, stream, hin, b_map, ws);
    hipLaunchKernelGGL(k2_denom,dim3(512),  dim3(1024), 0, stream, ws);
    hipLaunchKernelGGL(k3_main, dim3(8192), dim3(256),  0, stream, ws, out);
}

// Round 5
// 92.498 us; speedup vs baseline: 1.0232x; 1.0232x over previous
//
#include <hip/hip_runtime.h>
#include <math.h>

#define ALPHA 0.2f

typedef __attribute__((ext_vector_type(8))) short bf16x8;
typedef __attribute__((ext_vector_type(4))) float f32x4;
typedef __attribute__((ext_vector_type(4))) unsigned short us4;

// workspace layout (float offsets)
static constexpr size_t WS_ADJ  = 0;      // 1024 f32 adj_n
static constexpr size_t WS_WA1  = 1024;   // 32
static constexpr size_t WS_WA2  = 1056;   // 32  (contiguous with WA1)
static constexpr size_t WS_C12  = 1088;   // 2
static constexpr size_t WS_ADJT = 1664;   // 1024 bf16: adjT[j][i]
static constexpr size_t WS_WMF  = 2176;   // 1024 bf16: frag-ordered wm B-operand
static constexpr size_t WS_S1   = 2816;                     // N*H*W*V f32
static constexpr size_t WS_S2   = WS_S1 + (size_t)1048576;
static constexpr size_t WS_DEN  = WS_S2 + (size_t)1048576;  // [nh][i][j] = 1/denom

__device__ __forceinline__ unsigned short f2bf(float x){
    union { float f; unsigned u; } c; c.f = x;
    unsigned r = c.u + 0x7FFFu + ((c.u >> 16) & 1u);
    return (unsigned short)(r >> 16);
}

__global__ __launch_bounds__(1024) void k0_prep(const float* __restrict__ W_map,
    const float* __restrict__ b_map, const float* __restrict__ a_attn,
    const float* __restrict__ B_adj, float* __restrict__ ws)
{
    __shared__ float lds[1024];
    __shared__ float d12[32];
    int tid = threadIdx.x;
    int i = tid >> 5, j = tid & 31;
    float a = B_adj[tid] + (i == j ? 1.0f : 0.0f);
    lds[tid] = a; __syncthreads();
    for (int s = 512; s > 0; s >>= 1) { if (tid < s) lds[tid] = fmaxf(lds[tid], lds[tid + s]); __syncthreads(); }
    float mx = lds[0]; __syncthreads();
    lds[tid] = a; __syncthreads();
    for (int s = 512; s > 0; s >>= 1) { if (tid < s) lds[tid] = fminf(lds[tid], lds[tid + s]); __syncthreads(); }
    float mn = lds[0]; __syncthreads();
    float nrm = (a - mn) / (mx - mn);
    lds[tid] = nrm; __syncthreads();
    if (tid < 32) {
        float s = 0.f;
        for (int jj = 0; jj < 32; ++jj) s += lds[tid * 32 + jj];
        d12[tid] = 1.0f / sqrtf(s);
    }
    __syncthreads();
    float adjn = d12[i] * nrm * d12[j];
    ws[WS_ADJ + tid] = adjn;
    ((unsigned short*)(ws + WS_ADJT))[j * 32 + i] = f2bf(adjn);   // adjT[j][i]
    // frag-ordered wm B-operand: idx = q*512 + l*8 + e -> wm[t=8*(l>>4)+e][f=(l&15)+16q]
    {
        int q = tid >> 9, rem = tid & 511, ll = rem >> 3, e = rem & 7;
        int t = 8 * (ll >> 4) + e, f = (ll & 15) + 16 * q;
        ((unsigned short*)(ws + WS_WMF))[tid] = f2bf(W_map[t * 32 + f]);
    }
    if (tid < 32) {
        float w1 = 0.f, w2 = 0.f;
        for (int f = 0; f < 32; ++f) {
            w1 += W_map[tid * 32 + f] * a_attn[f];
            w2 += W_map[tid * 32 + f] * a_attn[32 + f];
        }
        ws[WS_WA1 + tid] = w1; ws[WS_WA2 + tid] = w2;
    }
    if (tid == 0) {
        float c1 = 0.f, c2 = 0.f;
        for (int f = 0; f < 32; ++f) { c1 += b_map[f] * a_attn[f]; c2 += b_map[f] * a_attn[32 + f]; }
        ws[WS_C12] = c1; ws[WS_C12 + 1] = c2;
    }
}

// s1/s2[n,h,w,i] = sum_t h[n,h,w,t,i]*wa[t] + c   (pure streaming, BW-bound)
__global__ __launch_bounds__(256) void k1_scores(const float* __restrict__ hin, float* __restrict__ ws)
{
    __shared__ float lwa1[32], lwa2[32];
    int tid = threadIdx.x;
    if (tid < 32) lwa1[tid] = ws[WS_WA1 + tid];
    else if (tid < 64) lwa2[tid - 32] = ws[WS_WA2 + (tid - 32)];
    __syncthreads();
    float c1 = ws[WS_C12], c2 = ws[WS_C12 + 1];
    int g = tid >> 5, lane = tid & 31;
    long site = (long)blockIdx.x * 8 + g;
    const float* hp = hin + site * 1024;
    float a1 = c1, a2 = c2;
#pragma unroll
    for (int t = 0; t < 32; ++t) {
        float x = hp[t * 32 + lane];
        a1 = fmaf(x, lwa1[t], a1);
        a2 = fmaf(x, lwa2[t], a2);
    }
    ws[WS_S1 + site * 32 + lane] = a1;
    ws[WS_S2 + site * 32 + lane] = a2;
}

// rden[nh,i,j] = 1 / sum_w exp(lrelu(s1[i,w]+s2[j,w]))
__global__ __launch_bounds__(1024) void k2_denom(float* __restrict__ ws)
{
    __shared__ float ls1[2048], ls2[2048];
    int tid = threadIdx.x;
    long nh = blockIdx.x;
    const float* s1 = ws + WS_S1 + nh * 2048;
    const float* s2 = ws + WS_S2 + nh * 2048;
    ls1[tid] = s1[tid]; ls1[tid + 1024] = s1[tid + 1024];
    ls2[tid] = s2[tid]; ls2[tid + 1024] = s2[tid + 1024];
    __syncthreads();
    int i = tid >> 5, j = tid & 31;
    float sum = 0.f;
#pragma unroll
    for (int w = 0; w < 64; ++w) {
        float e = ls1[w * 32 + i] + ls2[w * 32 + j];
        e = e > 0.f ? e : ALPHA * e;
        sum += __expf(e);
    }
    ws[WS_DEN + nh * 1024 + tid] = 1.0f / sum;
}

__device__ __forceinline__ float elu(float x) { return x > 0.f ? x : __expf(x) - 1.0f; }

__device__ __forceinline__ bf16x8 pack8(f32x4 a, f32x4 b){
    bf16x8 r;
    r[0]=(short)f2bf(a[0]); r[1]=(short)f2bf(a[1]); r[2]=(short)f2bf(a[2]); r[3]=(short)f2bf(a[3]);
    r[4]=(short)f2bf(b[0]); r[5]=(short)f2bf(b[1]); r[6]=(short)f2bf(b[2]); r[7]=(short)f2bf(b[3]);
    return r;
}
__device__ __forceinline__ void store_bf4(unsigned short* p, f32x4 v){
    us4 s; s[0]=f2bf(v[0]); s[1]=f2bf(v[1]); s[2]=f2bf(v[2]); s[3]=f2bf(v[3]);
    *(us4*)p = s;
}

// k3: one site per wave, 4 waves/block, BARRIER-FREE (only wave-local LDS for
// inter-stage fragment shuffles). A-operands gathered straight from global.
__global__ __launch_bounds__(256) void k3_main(const float* __restrict__ hin,
    const float* __restrict__ b_map, const float* __restrict__ ws, float* __restrict__ out)
{
    __shared__ unsigned short whT[4][32 * 40];   // per-wave Wh as [f][j] bf16 pad40
    __shared__ unsigned short mtT[4][32 * 40];   // per-wave M  as [j][j'] bf16 pad40

    const int tid = threadIdx.x;
    const int wid = tid >> 6, l = tid & 63;
    const long site = (long)blockIdx.x * 4 + wid;
    const int w = (int)(site & 63);
    const long nh = site >> 6;
    const int hh = (int)(nh & 63);
    const int n = (int)(nh >> 6);
    const int fr = l & 15, g = l >> 4;

    // --- issue all independent global loads up front ---
    const float* hp = hin + site * 1024;
    float hx[2][8];
#pragma unroll
    for (int p = 0; p < 2; ++p)
#pragma unroll
        for (int e = 0; e < 8; ++e)
            hx[p][e] = hp[(g * 8 + e) * 32 + fr + 16 * p];   // h[t][v], t=g*8+e, v=fr+16p

    const float* denp = ws + WS_DEN + nh * 1024;
    float dn[2][8];
#pragma unroll
    for (int p = 0; p < 2; ++p)
#pragma unroll
        for (int e = 0; e < 8; ++e)
            dn[p][e] = denp[(g * 8 + e) * 32 + fr + 16 * p]; // den[i][j'], i=g*8+e, j'=fr+16p

    f32x4 s1a = *(const f32x4*)(ws + WS_S1 + site * 32 + g * 8);
    f32x4 s1b = *(const f32x4*)(ws + WS_S1 + site * 32 + g * 8 + 4);
    float s2v[2] = { ws[WS_S2 + site * 32 + fr], ws[WS_S2 + site * 32 + fr + 16] };

    bf16x8 wmF[2], adjB[2];
    {
        const short* wf  = (const short*)(ws + WS_WMF);
        const short* adt = (const short*)(ws + WS_ADJT);
        wmF[0] = *(const bf16x8*)(wf + l * 8);
        wmF[1] = *(const bf16x8*)(wf + 512 + l * 8);
#pragma unroll
        for (int q = 0; q < 2; ++q)
            adjB[q] = *(const bf16x8*)(adt + (fr + 16 * q) * 32 + g * 8);
    }
    const float bb[2] = { b_map[fr], b_map[fr + 16] };

    // --- stage 1: Wh[j][f] = sum_t h[t][j] wm[t][f] + b[f] ---
    {
        bf16x8 a1[2];
#pragma unroll
        for (int p = 0; p < 2; ++p) {
            f32x4 lo = { hx[p][0], hx[p][1], hx[p][2], hx[p][3] };
            f32x4 hi = { hx[p][4], hx[p][5], hx[p][6], hx[p][7] };
            a1[p] = pack8(lo, hi);   // A[j=fr+16p][t=g*8+e]
        }
#pragma unroll
        for (int p = 0; p < 2; ++p)
#pragma unroll
            for (int q = 0; q < 2; ++q) {
                f32x4 c = { bb[q], bb[q], bb[q], bb[q] };
                c = __builtin_amdgcn_mfma_f32_16x16x32_bf16(a1[p], wmF[q], c, 0, 0, 0);
                // D rows j=4g+r+16p, col f=fr+16q -> store transposed [f][j]
                store_bf4(&whT[wid][(fr + 16 * q) * 40 + 4 * g + 16 * p], c);
            }
    }

    // --- stage 2: M[j'][j] = sum_i at[i][j'] adj[i][j], at in-register ---
    {
        bf16x8 a2[2];
#pragma unroll
        for (int p = 0; p < 2; ++p) {
            f32x4 t0, t1;
#pragma unroll
            for (int e = 0; e < 4; ++e) {
                float ea = s1a[e] + s2v[p]; ea = ea > 0.f ? ea : ALPHA * ea;
                float eb = s1b[e] + s2v[p]; eb = eb > 0.f ? eb : ALPHA * eb;
                t0[e] = __expf(ea) * dn[p][e];
                t1[e] = __expf(eb) * dn[p][e + 4];
            }
            a2[p] = pack8(t0, t1);   // A[j'=fr+16p][i=g*8+e]
        }
#pragma unroll
        for (int p = 0; p < 2; ++p)
#pragma unroll
            for (int q = 0; q < 2; ++q) {
                f32x4 c = { 0.f, 0.f, 0.f, 0.f };
                c = __builtin_amdgcn_mfma_f32_16x16x32_bf16(a2[p], adjB[q], c, 0, 0, 0);
                // D rows j'=4g+r+16p, col j=fr+16q -> store [j][j']
                store_bf4(&mtT[wid][(fr + 16 * q) * 40 + 4 * g + 16 * p], c);
            }
    }

    // --- stage 3: O[f][j] = sum_j' WhT[f][j'] M[j'][j] ---
    {
        bf16x8 a3[2], b3[2];
#pragma unroll
        for (int p = 0; p < 2; ++p)
            a3[p] = *(const bf16x8*)&whT[wid][(fr + 16 * p) * 40 + g * 8];
#pragma unroll
        for (int q = 0; q < 2; ++q)
            b3[q] = *(const bf16x8*)&mtT[wid][(fr + 16 * q) * 40 + g * 8];
        const int hhi = hh >> 5, f3 = hh & 31;
#pragma unroll
        for (int p = 0; p < 2; ++p)
#pragma unroll
            for (int q = 0; q < 2; ++q) {
                f32x4 c = { 0.f, 0.f, 0.f, 0.f };
                c = __builtin_amdgcn_mfma_f32_16x16x32_bf16(a3[p], b3[q], c, 0, 0, 0);
#pragma unroll
                for (int r = 0; r < 4; ++r) {
                    int f = 16 * p + 4 * g + r;
                    int w3 = f * 2 + hhi;
                    __builtin_nontemporal_store(elu(c[r]),
                        out + ((((long)n * 64 + w) * 64 + w3) * 32 + f3) * 32 + fr + 16 * q);
                }
            }
    }
}

extern "C" void kernel_launch(void* const* d_in, const int* in_sizes, int n_in,
                              void* d_out, int out_size, void* d_ws, size_t ws_size,
                              hipStream_t stream) {
    (void)in_sizes; (void)n_in; (void)out_size; (void)ws_size;
    const float* hin    = (const float*)d_in[0];
    const float* W_map  = (const float*)d_in[1];
    const float* b_map  = (const float*)d_in[2];
    const float* a_attn = (const float*)d_in[3];
    const float* B_adj  = (const float*)d_in[4];
    float* out = (float*)d_out;
    float* ws  = (float*)d_ws;

    hipLaunchKernelGGL(k0_prep,   dim3(1),    dim3(1024), 0, stream, W_map, b_map, a_attn, B_adj, ws);
    hipLaunchKernelGGL(k1_scores, dim3(4096), dim3(256),  0, stream, hin, ws);
    hipLaunchKernelGGL(k2_denom,  dim3(512),  dim3(1024), 0, stream, ws);
    hipLaunchKernelGGL(k3_main,   dim3(8192), dim3(256),  0, stream, hin, b_map, ws, out);
}

// Round 6
// 70.678 us; speedup vs baseline: 1.3390x; 1.3087x over previous
//
#include <hip/hip_runtime.h>
#include <math.h>

typedef __attribute__((ext_vector_type(8))) short bf16x8;
typedef __attribute__((ext_vector_type(16))) float f32x16;
typedef __attribute__((ext_vector_type(4))) float f32x4;

// ws layout (float offsets)
static constexpr size_t WS_WA   = 0;    // 64: wa1[32] ‖ wa2[32]
static constexpr size_t WS_C12  = 64;   // 2: b.a1, b.a2
static constexpr size_t WS_WMF  = 96;   // 1024 u16 (512 f): stage-1 B frags  [kap][l][e] = wm[t][f], t=16kap+8*(l>>5)+e, f=l&31
static constexpr size_t WS_ADJF = 608;  // 1024 u16: stage-2 B frags          [kap][l][e] = adj_n[i][i2], i=16kap+8*(l>>5)+e, i2=l&31

__device__ __forceinline__ unsigned short f2bf(float x){
    union { float f; unsigned u; } c; c.f = x;
    unsigned r = c.u + 0x7FFFu + ((c.u >> 16) & 1u);
    return (unsigned short)(r >> 16);
}
__device__ __forceinline__ unsigned pk2(float a, float b){
    return (unsigned)f2bf(a) | ((unsigned)f2bf(b) << 16);
}
__device__ __forceinline__ float bf2f(unsigned short v){
    return __uint_as_float(((unsigned)v) << 16);
}
__device__ __forceinline__ float elu(float x){ return x > 0.f ? x : __expf(x) - 1.0f; }
__device__ __forceinline__ float lrelu(float x){ return fmaxf(x, 0.2f * x); }

__global__ __launch_bounds__(1024) void k0_prep(const float* __restrict__ W_map,
    const float* __restrict__ b_map, const float* __restrict__ a_attn,
    const float* __restrict__ B_adj, float* __restrict__ ws)
{
    __shared__ float lds[1024];
    __shared__ float d12[32];
    int tid = threadIdx.x;
    int i = tid >> 5, j = tid & 31;
    float a = B_adj[tid] + (i == j ? 1.0f : 0.0f);
    lds[tid] = a; __syncthreads();
    for (int s = 512; s > 0; s >>= 1) { if (tid < s) lds[tid] = fmaxf(lds[tid], lds[tid + s]); __syncthreads(); }
    float mx = lds[0]; __syncthreads();
    lds[tid] = a; __syncthreads();
    for (int s = 512; s > 0; s >>= 1) { if (tid < s) lds[tid] = fminf(lds[tid], lds[tid + s]); __syncthreads(); }
    float mn = lds[0]; __syncthreads();
    lds[tid] = (a - mn) / (mx - mn); __syncthreads();
    if (tid < 32) {
        float s = 0.f;
        for (int jj = 0; jj < 32; ++jj) s += lds[tid * 32 + jj];
        d12[tid] = 1.0f / sqrtf(s);
    }
    __syncthreads();

    // frag-ordered constants: idx = kap*512 + l*8 + e
    {
        int kap = tid >> 9, rem = tid & 511, l = rem >> 3, e = rem & 7;
        int krow = 16 * kap + 8 * (l >> 5) + e;   // t (for wm) / i (for adj)
        int col  = l & 31;                        // f / i2
        ((unsigned short*)(ws + WS_WMF))[tid] = f2bf(W_map[krow * 32 + col]);
        float aij = B_adj[krow * 32 + col] + (krow == col ? 1.0f : 0.0f);
        float adjv = d12[krow] * ((aij - mn) / (mx - mn)) * d12[col];
        ((unsigned short*)(ws + WS_ADJF))[tid] = f2bf(adjv);
    }
    if (tid < 32) {
        float w1 = 0.f, w2 = 0.f;
        for (int f = 0; f < 32; ++f) {
            w1 += W_map[tid * 32 + f] * a_attn[f];
            w2 += W_map[tid * 32 + f] * a_attn[32 + f];
        }
        ws[WS_WA + tid] = w1; ws[WS_WA + 32 + tid] = w2;
    }
    if (tid == 0) {
        float c1 = 0.f, c2 = 0.f;
        for (int f = 0; f < 32; ++f) { c1 += b_map[f] * a_attn[f]; c2 += b_map[f] * a_attn[32 + f]; }
        ws[WS_C12] = c1; ws[WS_C12 + 1] = c2;
    }
}

// D(32x32 mfma, col=l&31) -> next-stage A/B frag (idx=l&31, k=16*KAP+8*hi+e).
// Rows needed by a lane: 4 local regs + 4 from partner lane (l^32).
template<int KAP>
__device__ __forceinline__ bf16x8 xform(const f32x16& d, int hi){
    unsigned b0 = pk2(d[8*KAP+0], d[8*KAP+1]);
    unsigned b1 = pk2(d[8*KAP+2], d[8*KAP+3]);
    unsigned b2 = pk2(d[8*KAP+4], d[8*KAP+5]);
    unsigned b3 = pk2(d[8*KAP+6], d[8*KAP+7]);
    unsigned pb0 = (unsigned)__shfl_xor((int)b0, 32, 64);
    unsigned pb1 = (unsigned)__shfl_xor((int)b1, 32, 64);
    unsigned pb2 = (unsigned)__shfl_xor((int)b2, 32, 64);
    unsigned pb3 = (unsigned)__shfl_xor((int)b3, 32, 64);
    union { unsigned u[4]; bf16x8 v; } t;
    t.u[0] = hi ? pb2 : b0;
    t.u[1] = hi ? pb3 : b1;
    t.u[2] = hi ? b2 : pb0;
    t.u[3] = hi ? b3 : pb1;
    return t.v;
}

// One block = one (n,hh) row: h staged to LDS (bf16, frag order) ONCE; everything
// else on-chip; only final out stores go to global.
__global__ __launch_bounds__(1024) void kfused(const float* __restrict__ hin,
    const float* __restrict__ b_map, const float* __restrict__ ws, float* __restrict__ out)
{
    __shared__ unsigned short hbf[64 * 1024];   // 128 KB: [s][kap][l][e]
    __shared__ float s1L[64 * 32];              // 8 KB  [w][i]
    __shared__ float s2L[64 * 32];              // 8 KB
    __shared__ float rdenL[32 * 32];            // 4 KB  [i][j]
    __shared__ float waL[64];

    const int tid = threadIdx.x;
    const int wv = tid >> 6, l = tid & 63;
    const int c = l & 31, hi = l >> 5;
    const int nh = blockIdx.x;                  // n*64 + hh
    const int hh = nh & 63, n = nh >> 6;

    if (tid < 64) waL[tid] = ws[WS_WA + tid];
    const float c1 = ws[WS_C12], c2 = ws[WS_C12 + 1];
    const float bc = b_map[c];

    bf16x8 B1f[2], B2f[2];
    {
        const unsigned short* wmf = (const unsigned short*)(ws + WS_WMF);
        const unsigned short* adf = (const unsigned short*)(ws + WS_ADJF);
        B1f[0] = *(const bf16x8*)(wmf + l * 8);
        B1f[1] = *(const bf16x8*)(wmf + 512 + l * 8);
        B2f[0] = *(const bf16x8*)(adf + l * 8);
        B2f[1] = *(const bf16x8*)(adf + 512 + l * 8);
    }

    // ---- phase A: stage h row -> hbf (bf16, frag order) ----
    {
        const float* hrow = hin + (long)nh * 65536;
        unsigned* hb32 = (unsigned*)hbf;
#pragma unroll
        for (int it = 0; it < 8; ++it) {
            int slot = it * 1024 + tid;
            int s = slot >> 7, r = slot & 127;
            int t = (r >> 3) * 2, v0 = (r & 7) * 4;
            f32x4 x0 = *(const f32x4*)(hrow + s * 1024 + t * 32 + v0);
            f32x4 x1 = *(const f32x4*)(hrow + s * 1024 + (t + 1) * 32 + v0);
            int kap = t >> 4, e = t & 7, lb = 32 * ((t >> 3) & 1);
#pragma unroll
            for (int cc = 0; cc < 4; ++cc) {
                int u16i = s * 1024 + kap * 512 + (v0 + cc + lb) * 8 + e;  // e even
                hb32[u16i >> 1] = pk2(x0[cc], x1[cc]);
            }
        }
    }
    __syncthreads();

    // ---- phase A2: s1/s2 per site from staged frags ----
    {
        float wa1v[16], wa2v[16];
#pragma unroll
        for (int kk = 0; kk < 16; ++kk) {
            int t = 16 * (kk >> 3) + 8 * hi + (kk & 7);
            wa1v[kk] = waL[t]; wa2v[kk] = waL[32 + t];
        }
#pragma unroll
        for (int k = 0; k < 4; ++k) {
            int s = wv * 4 + k;
            const unsigned short* fp = hbf + s * 1024;
            bf16x8 f0 = *(const bf16x8*)(fp + l * 8);
            bf16x8 f1 = *(const bf16x8*)(fp + 512 + l * 8);
            float p1 = 0.f, p2 = 0.f;
#pragma unroll
            for (int e = 0; e < 8; ++e) {
                float x = bf2f((unsigned short)f0[e]);
                p1 = fmaf(x, wa1v[e], p1); p2 = fmaf(x, wa2v[e], p2);
            }
#pragma unroll
            for (int e = 0; e < 8; ++e) {
                float x = bf2f((unsigned short)f1[e]);
                p1 = fmaf(x, wa1v[8 + e], p1); p2 = fmaf(x, wa2v[8 + e], p2);
            }
            p1 += __shfl_xor(p1, 32, 64);
            p2 += __shfl_xor(p2, 32, 64);
            if (!hi) { s1L[s * 32 + c] = p1 + c1; s2L[s * 32 + c] = p2 + c2; }
        }
    }
    __syncthreads();

    // ---- phase B: rden[i][j] = 1/sum_w exp(lrelu(s1[w,i]+s2[w,j])) ----
    {
        int i = tid >> 5, j = tid & 31;
        float sum = 0.f;
#pragma unroll
        for (int w = 0; w < 64; ++w)
            sum += __expf(lrelu(s1L[w * 32 + i] + s2L[w * 32 + j]));
        rdenL[tid] = 1.0f / sum;
    }
    __syncthreads();

    // ---- phase C: per site, 3 chained 32x32 matmuls, store out ----
    const int hh5 = hh >> 5, f3 = hh & 31;
#pragma unroll 1
    for (int k = 0; k < 4; ++k) {
        const int s = wv * 4 + k;
        const unsigned short* fp = hbf + s * 1024;
        bf16x8 a10 = *(const bf16x8*)(fp + l * 8);
        bf16x8 a11 = *(const bf16x8*)(fp + 512 + l * 8);

        // stage 1: D1[j][f] = sum_t h[t][j] wm[t][f] + b[f]
        f32x16 d1;
#pragma unroll
        for (int r = 0; r < 16; ++r) d1[r] = bc;
        d1 = __builtin_amdgcn_mfma_f32_32x32x16_bf16(a10, B1f[0], d1, 0, 0, 0);
        d1 = __builtin_amdgcn_mfma_f32_32x32x16_bf16(a11, B1f[1], d1, 0, 0, 0);
        bf16x8 A3_0 = xform<0>(d1, hi);
        bf16x8 A3_1 = xform<1>(d1, hi);

        // stage 2: D2[j][i2] = sum_i attn[i,j] adj[i,i2]; attn built in-register
        const float s2c = s2L[s * 32 + c];
        f32x4 sa = *(const f32x4*)&s1L[s * 32 + 8 * hi];
        f32x4 sb = *(const f32x4*)&s1L[s * 32 + 8 * hi + 4];
        f32x4 sc_ = *(const f32x4*)&s1L[s * 32 + 16 + 8 * hi];
        f32x4 sd = *(const f32x4*)&s1L[s * 32 + 16 + 8 * hi + 4];
        float q[16];
#pragma unroll
        for (int e = 0; e < 4; ++e) {
            int i0 = 8 * hi + e, i1 = 8 * hi + 4 + e, i2i = 16 + 8 * hi + e, i3 = 16 + 8 * hi + 4 + e;
            q[e]      = __expf(lrelu(sa[e] + s2c)) * rdenL[i0 * 32 + c];
            q[4 + e]  = __expf(lrelu(sb[e] + s2c)) * rdenL[i1 * 32 + c];
            q[8 + e]  = __expf(lrelu(sc_[e] + s2c)) * rdenL[i2i * 32 + c];
            q[12 + e] = __expf(lrelu(sd[e] + s2c)) * rdenL[i3 * 32 + c];
        }
        union { unsigned u[4]; bf16x8 v; } A2_0, A2_1;
        A2_0.u[0] = pk2(q[0], q[1]);  A2_0.u[1] = pk2(q[2], q[3]);
        A2_0.u[2] = pk2(q[4], q[5]);  A2_0.u[3] = pk2(q[6], q[7]);
        A2_1.u[0] = pk2(q[8], q[9]);  A2_1.u[1] = pk2(q[10], q[11]);
        A2_1.u[2] = pk2(q[12], q[13]); A2_1.u[3] = pk2(q[14], q[15]);

        f32x16 d2;
#pragma unroll
        for (int r = 0; r < 16; ++r) d2[r] = 0.f;
        d2 = __builtin_amdgcn_mfma_f32_32x32x16_bf16(A2_0.v, B2f[0], d2, 0, 0, 0);
        d2 = __builtin_amdgcn_mfma_f32_32x32x16_bf16(A2_1.v, B2f[1], d2, 0, 0, 0);
        bf16x8 B3_0 = xform<0>(d2, hi);
        bf16x8 B3_1 = xform<1>(d2, hi);

        // stage 3: D3[f][i2] = sum_j Wh[j][f] M[j][i2]
        f32x16 d3;
#pragma unroll
        for (int r = 0; r < 16; ++r) d3[r] = 0.f;
        d3 = __builtin_amdgcn_mfma_f32_32x32x16_bf16(A3_0, B3_0, d3, 0, 0, 0);
        d3 = __builtin_amdgcn_mfma_f32_32x32x16_bf16(A3_1, B3_1, d3, 0, 0, 0);

        // store: out[(((n*64+w)*64 + f*2+hh5)*32 + f3)*32 + c]
        float* ob = out + (((long)(n * 64 + s) * 64) * 32 + f3) * 32 + c;
#pragma unroll
        for (int r = 0; r < 16; ++r) {
            int f = (r & 3) + 8 * (r >> 2) + 4 * hi;
            ob[(f * 2 + hh5) * 1024] = elu(d3[r]);
        }
    }
}

extern "C" void kernel_launch(void* const* d_in, const int* in_sizes, int n_in,
                              void* d_out, int out_size, void* d_ws, size_t ws_size,
                              hipStream_t stream) {
    (void)in_sizes; (void)n_in; (void)out_size; (void)ws_size;
    const float* hin    = (const float*)d_in[0];
    const float* W_map  = (const float*)d_in[1];
    const float* b_map  = (const float*)d_in[2];
    const float* a_attn = (const float*)d_in[3];
    const float* B_adj  = (const float*)d_in[4];
    float* out = (float*)d_out;
    float* ws  = (float*)d_ws;

    hipLaunchKernelGGL(k0_prep, dim3(1),   dim3(1024), 0, stream, W_map, b_map, a_attn, B_adj, ws);
    hipLaunchKernelGGL(kfused,  dim3(512), dim3(1024), 0, stream, hin, b_map, ws, out);
}